// Round 1
// baseline (1039.227 us; speedup 1.0000x reference)
//
#include <hip/hip_runtime.h>

#define D    4096
#define H    32
#define KVH  8
#define HD   128
#define GRP  4          // H / KVH
#define PAGE 256        // tokens per cache block
#define VOCAB 32000

// ---------------- wave helpers ----------------

__device__ __forceinline__ float wave_reduce_sum(float v) {
#pragma unroll
    for (int off = 32; off > 0; off >>= 1) v += __shfl_xor(v, off, 64);
    return v;
}

// dot(Wrow[0:4096], x[0:4096]) across one 64-lane wave, float4 loads
__device__ __forceinline__ float wave_dot4096(const float* __restrict__ Wrow,
                                              const float* __restrict__ x,
                                              int lane) {
    const float4* w4 = (const float4*)Wrow;
    const float4* x4 = (const float4*)x;
    float acc = 0.f;
#pragma unroll
    for (int it = 0; it < 16; ++it) {
        float4 w  = w4[it * 64 + lane];
        float4 xv = x4[it * 64 + lane];
        acc = fmaf(w.x, xv.x, acc);
        acc = fmaf(w.y, xv.y, acc);
        acc = fmaf(w.z, xv.z, acc);
        acc = fmaf(w.w, xv.w, acc);
    }
    return wave_reduce_sum(acc);
}

// ---------------- kernel 1: q/k/v projections ----------------
// rows 0..4095 -> q, 4096..5119 -> k_new, 5120..6143 -> v_new
__global__ void qkv_kernel(const int* __restrict__ token_id,
                           const float* __restrict__ embed,
                           const float* __restrict__ Wq,
                           const float* __restrict__ Wk,
                           const float* __restrict__ Wv,
                           float* __restrict__ q,
                           float* __restrict__ kn,
                           float* __restrict__ vn) {
    const int lane = threadIdx.x & 63;
    const int wave = threadIdx.x >> 6;
    const int row  = blockIdx.x * 4 + wave;
    const float* x = embed + (size_t)token_id[0] * D;
    const float* Wrow;
    float* outp;
    if (row < H * HD)               { Wrow = Wq + (size_t)row * D;                 outp = q  + row; }
    else if (row < (H + KVH) * HD)  { int r = row - H * HD;
                                      Wrow = Wk + (size_t)r * D;                   outp = kn + r; }
    else                            { int r = row - (H + KVH) * HD;
                                      Wrow = Wv + (size_t)r * D;                   outp = vn + r; }
    float acc = wave_dot4096(Wrow, x, lane);
    if (lane == 0) *outp = acc;
}

// ---------------- kernel 2: attention partials (flash-decode) ----------------
// grid = KVH * 32 blocks; block = 256 (4 waves); each wave = 32 tokens.
// partial index pidx = chunk*4 + wave in [0,128) per head.
__global__ void attn_partial_kernel(const int* __restrict__ pos_p,
                                    const int* __restrict__ block_table,
                                    const float* __restrict__ q,
                                    const float* __restrict__ kn,
                                    const float* __restrict__ vn,
                                    const float* __restrict__ k_cache,
                                    const float* __restrict__ v_cache,
                                    float* __restrict__ pm,
                                    float* __restrict__ ps,
                                    float* __restrict__ po) {
    const int kh    = blockIdx.x >> 5;
    const int chunk = blockIdx.x & 31;
    const int lane  = threadIdx.x & 63;
    const int wave  = threadIdx.x >> 6;
    const int pos   = pos_p[0];
    const float scale = 0.088388347648318447f;  // 1/sqrt(128)

    float2 qv[GRP];
#pragma unroll
    for (int g = 0; g < GRP; ++g)
        qv[g] = ((const float2*)(q + (size_t)(kh * GRP + g) * HD))[lane];

    float m[GRP], s[GRP];
    float2 o2[GRP];
#pragma unroll
    for (int g = 0; g < GRP; ++g) { m[g] = -INFINITY; s[g] = 0.f; o2[g] = make_float2(0.f, 0.f); }

    const int t0 = chunk * 128 + wave * 32;
    for (int i = 0; i < 32; ++i) {
        int t = t0 + i;
        if (t > pos) break;
        const float *Kt, *Vt;
        if (t == pos) { Kt = kn + kh * HD; Vt = vn + kh * HD; }
        else {
            int blk = block_table[t >> 8];
            size_t base = ((((size_t)blk * PAGE) + (t & (PAGE - 1))) * KVH + kh) * HD;
            Kt = k_cache + base;
            Vt = v_cache + base;
        }
        float2 kk = ((const float2*)Kt)[lane];
        float2 vv = ((const float2*)Vt)[lane];
#pragma unroll
        for (int g = 0; g < GRP; ++g) {
            float sc = fmaf(qv[g].x, kk.x, qv[g].y * kk.y);
            sc = wave_reduce_sum(sc) * scale;
            float mn   = fmaxf(m[g], sc);
            float corr = __expf(m[g] - mn);   // m=-inf on first token -> corr=0
            float p    = __expf(sc - mn);
            s[g]   = fmaf(s[g], corr, p);
            o2[g].x = fmaf(o2[g].x, corr, p * vv.x);
            o2[g].y = fmaf(o2[g].y, corr, p * vv.y);
            m[g] = mn;
        }
    }

    const int pidx = chunk * 4 + wave;   // 0..127
#pragma unroll
    for (int g = 0; g < GRP; ++g) {
        int h = kh * GRP + g;
        if (lane == 0) {
            pm[h * 128 + pidx] = m[g];
            ps[h * 128 + pidx] = s[g];
        }
        float2* dst = (float2*)(po + (((size_t)h * 128) + pidx) * HD);
        dst[lane] = o2[g];
    }
}

// ---------------- kernel 3: merge partials ----------------
// grid = 32 (heads); block = 128 threads (one per dim and one per partial)
__global__ void attn_combine_kernel(const float* __restrict__ pm,
                                    const float* __restrict__ ps,
                                    const float* __restrict__ po,
                                    float* __restrict__ attn) {
    const int h = blockIdx.x;
    const int t = threadIdx.x;  // 0..127
    __shared__ float red[128];
    __shared__ float w[128];

    float myM = pm[h * 128 + t];
    red[t] = myM;
    __syncthreads();
#pragma unroll
    for (int off = 64; off > 0; off >>= 1) {
        if (t < off) red[t] = fmaxf(red[t], red[t + off]);
        __syncthreads();
    }
    float M = red[0];
    __syncthreads();

    float e = __expf(myM - M);           // -inf partial -> 0
    red[t] = ps[h * 128 + t] * e;
    __syncthreads();
#pragma unroll
    for (int off = 64; off > 0; off >>= 1) {
        if (t < off) red[t] += red[t + off];
        __syncthreads();
    }
    float S = red[0];

    w[t] = e / S;
    __syncthreads();

    float acc = 0.f;
    for (int p = 0; p < 128; ++p)
        acc += po[(((size_t)h * 128) + p) * HD + t] * w[p];
    attn[h * HD + t] = acc;
}

// ---------------- kernel 4: out = Wo @ attn, xo = x + out ----------------
__global__ void out_kernel(const int* __restrict__ token_id,
                           const float* __restrict__ embed,
                           const float* __restrict__ Wo,
                           const float* __restrict__ attn,
                           float* __restrict__ xo) {
    const int lane = threadIdx.x & 63;
    const int wave = threadIdx.x >> 6;
    const int row  = blockIdx.x * 4 + wave;
    float acc = wave_dot4096(Wo + (size_t)row * D, attn, lane);
    if (lane == 0) xo[row] = acc + embed[(size_t)token_id[0] * D + row];
}

// ---------------- kernel 5: logits = W_lm @ xo ----------------
__global__ void lm_kernel(const float* __restrict__ W_lm,
                          const float* __restrict__ xo,
                          float* __restrict__ logits) {
    const int lane = threadIdx.x & 63;
    const int wave = threadIdx.x >> 6;
    const int row  = blockIdx.x * 4 + wave;
    float acc = wave_dot4096(W_lm + (size_t)row * D, xo, lane);
    if (lane == 0) logits[row] = acc;
}

// ---------------- launch ----------------
extern "C" void kernel_launch(void* const* d_in, const int* in_sizes, int n_in,
                              void* d_out, int out_size, void* d_ws, size_t ws_size,
                              hipStream_t stream) {
    const int*   token_id    = (const int*)d_in[0];
    const int*   pos         = (const int*)d_in[1];
    const int*   block_table = (const int*)d_in[2];
    const float* embed       = (const float*)d_in[3];
    const float* Wq          = (const float*)d_in[4];
    const float* Wk          = (const float*)d_in[5];
    const float* Wv          = (const float*)d_in[6];
    const float* Wo          = (const float*)d_in[7];
    const float* W_lm        = (const float*)d_in[8];
    const float* k_cache     = (const float*)d_in[9];
    const float* v_cache     = (const float*)d_in[10];
    float* logits = (float*)d_out;

    float* ws   = (float*)d_ws;
    float* q    = ws;            // 4096
    float* kn   = ws + 4096;     // 1024
    float* vn   = ws + 5120;     // 1024
    float* attn = ws + 6144;     // 4096
    float* xo   = ws + 10240;    // 4096
    float* pm   = ws + 14336;    // 32*128
    float* ps_  = ws + 18432;    // 32*128
    float* po   = ws + 22528;    // 32*128*128 = 524288

    hipLaunchKernelGGL(qkv_kernel, dim3((H + 2 * KVH) * HD / 4), dim3(256), 0, stream,
                       token_id, embed, Wq, Wk, Wv, q, kn, vn);
    hipLaunchKernelGGL(attn_partial_kernel, dim3(KVH * 32), dim3(256), 0, stream,
                       pos, block_table, q, kn, vn, k_cache, v_cache, pm, ps_, po);
    hipLaunchKernelGGL(attn_combine_kernel, dim3(H), dim3(128), 0, stream,
                       pm, ps_, po, attn);
    hipLaunchKernelGGL(out_kernel, dim3(D / 4), dim3(256), 0, stream,
                       token_id, embed, Wo, attn, xo);
    hipLaunchKernelGGL(lm_kernel, dim3(VOCAB / 4), dim3(256), 0, stream,
                       W_lm, xo, logits);
}